// Round 4
// baseline (122.996 us; speedup 1.0000x reference)
//
#include <hip/hip_runtime.h>
#include <cstdint>
#include <cstddef>

#define N_ENT 100000
#define DIM 128
#define BSZ 256
#define FSZ 20000
#define BM 64
#define NBLK 1563            // ceil(N_ENT / BM)
#define NBLK_PAD 1568
#define MCAP 8192

typedef __attribute__((ext_vector_type(8))) short bf16x8;
typedef __attribute__((ext_vector_type(4))) float f32x4;

// ---------------- ws layout ----------------
#define WS_QALL 0                               // [512][128] f32 exact queries
#define WS_QSQ  (512 * DIM * 4)                 // [512] f32
#define WS_THR  (WS_QSQ + 512 * 4)              // [512] f32
#define WS_THC  (WS_THR + 512 * 4)              // [512] f32  (thr - qsq) * 0.5
#define WS_CNT  (WS_THC + 512 * 4)              // [512] int  (atomic fallback)
#define WS_MCNT (WS_CNT + 512 * 4)              // [1] int + pad
#define WS_MATCH (WS_MCNT + 16)                 // [MCAP] int2
#define WS_QBF  (WS_MATCH + MCAP * 8)           // [512][128] bf16
#define WS_PART (WS_QBF + 512 * DIM * 2 + 64)   // [512][NBLK_PAD] u16 partial counts
#define WS_NEED (WS_PART + 512 * NBLK_PAD * 2)

__device__ inline unsigned short f2bf(float x) {
    union { float f; uint32_t u; } v; v.f = x;
    uint32_t u = v.u;
    u += 0x7fffu + ((u >> 16) & 1);   // RNE
    return (unsigned short)(u >> 16);
}

__global__ __launch_bounds__(128) void k_prep(
    const float* __restrict__ ent, const float* __restrict__ rel,
    const int* __restrict__ heads, const int* __restrict__ rels, const int* __restrict__ tails,
    float* __restrict__ qall, float* __restrict__ qsq, float* __restrict__ thr,
    float* __restrict__ thc, int* __restrict__ cnt, int* __restrict__ mcnt,
    unsigned short* __restrict__ qbf)
{
    int b = blockIdx.x;
    int d = threadIdx.x;
    if (b == 0 && d == 0) *mcnt = 0;
    int h = heads[b], r = rels[b], t = tails[b];
    float eh = ent[(size_t)h * DIM + d];
    float er = rel[(size_t)r * DIM + d];
    float et = ent[(size_t)t * DIM + d];
    float diff = eh + er - et;
    float q = er - et;
    float p = eh + er;
    qall[(size_t)b * DIM + d] = q;
    qall[(size_t)(BSZ + b) * DIM + d] = -p;
    qbf[(size_t)b * DIM + d] = f2bf(q);
    qbf[(size_t)(BSZ + b) * DIM + d] = f2bf(-p);
    float s0 = diff * diff, s1 = q * q, s2 = p * p;
    #pragma unroll
    for (int off = 32; off; off >>= 1) {
        s0 += __shfl_xor(s0, off);
        s1 += __shfl_xor(s1, off);
        s2 += __shfl_xor(s2, off);
    }
    __shared__ float part[2][3];
    int wave = threadIdx.x >> 6, lane = threadIdx.x & 63;
    if (lane == 0) { part[wave][0] = s0; part[wave][1] = s1; part[wave][2] = s2; }
    __syncthreads();
    if (threadIdx.x == 0) {
        float tsq = part[0][0] + part[1][0];
        float qq  = part[0][1] + part[1][1];
        float pp  = part[0][2] + part[1][2];
        float th = fmaxf(tsq, 1e-12f);
        thr[b] = th; thr[BSZ + b] = th;
        qsq[b] = qq; qsq[BSZ + b] = pp;
        thc[b] = (th - qq) * 0.5f;
        thc[BSZ + b] = (th - pp) * 0.5f;
        cnt[b] = 0;  cnt[BSZ + b] = 0;
    }
}

__global__ __launch_bounds__(256) void k_scanf(
    const int* __restrict__ heads, const int* __restrict__ rels, const int* __restrict__ tails,
    const int* __restrict__ fh, const int* __restrict__ fr, const int* __restrict__ ft,
    int* __restrict__ mcnt, int2* __restrict__ match)
{
    __shared__ int hh[BSZ], rr[BSZ], tt[BSZ];
    int tid = threadIdx.x;
    hh[tid] = heads[tid]; rr[tid] = rels[tid]; tt[tid] = tails[tid];
    __syncthreads();
    int f = blockIdx.x * 256 + tid;
    if (f >= FSZ) return;
    int vr = fr[f], vt = ft[f], vh = fh[f];
    for (int b = 0; b < BSZ; b++) {
        int rb = rr[b];
        if (vr == rb && vt == tt[b]) {
            int p = atomicAdd(mcnt, 1);
            if (p < MCAP) match[p] = make_int2(b, vh);
        }
        if (vr == rb && vh == hh[b]) {
            int p = atomicAdd(mcnt, 1);
            if (p < MCAP) match[p] = make_int2(BSZ + b, vt);
        }
    }
}

// MFMA count: 64-entity tile/block, 4 waves x 128 query cols each.
// Counts accumulate in 8 per-lane registers; NO memory ops in the chunk loop
// except the prefetched B loads. Flush once at the end: contention-free
// per-block u16 partials (USE_PART) or atomic fallback.
template<bool USE_PART>
__global__ __launch_bounds__(256, 4) void k_count(
    const float* __restrict__ ent,
    const unsigned short* __restrict__ qbf,
    const float* __restrict__ thc,
    int* __restrict__ cnt, unsigned short* __restrict__ part)
{
    __shared__ __align__(16) char alds[BM * 256];   // 64 rows x 128 bf16, 16B-slot XOR swizzle
    __shared__ float esqh_lds[BM];                  // 0.5 * ||e_row||^2
    int tid = threadIdx.x;
    int lane = tid & 63, wave = tid >> 6;
    int base = blockIdx.x * BM;

    // B chunk-0 prefetch + per-col thresholds (hoisted out of the loop)
    int colq = wave * 128 + (lane & 15);
    const unsigned short* qb = qbf + (size_t)colq * DIM + (lane >> 4) * 8;
    bf16x8 bcur[4], bnext[4];
    #pragma unroll
    for (int ks = 0; ks < 4; ks++)
        bcur[ks] = *(const bf16x8*)(qb + ks * 32);
    float tcv[8];
    #pragma unroll
    for (int c = 0; c < 8; c++) tcv[c] = thc[colq + c * 16];

    // stage A: 4 threads per row, 128B each, fully coalesced
    int row = tid >> 2, qtr = tid & 3;
    int n = base + row;
    bool valid = n < N_ENT;
    const float4* src = (const float4*)(ent + (size_t)n * DIM) + qtr * 8;
    float4 v[8];
    float ssq = 0.f;
    #pragma unroll
    for (int j = 0; j < 8; j++) {
        v[j] = valid ? src[j] : make_float4(0.f, 0.f, 0.f, 0.f);
        ssq += v[j].x * v[j].x + v[j].y * v[j].y + v[j].z * v[j].z + v[j].w * v[j].w;
    }
    ssq += __shfl_xor(ssq, 1);
    ssq += __shfl_xor(ssq, 2);
    if (qtr == 0) esqh_lds[row] = valid ? ssq * 0.5f : 1.5e38f;
    #pragma unroll
    for (int jp = 0; jp < 4; jp++) {
        uint4 w;
        w.x = (uint32_t)f2bf(v[2*jp    ].x) | ((uint32_t)f2bf(v[2*jp    ].y) << 16);
        w.y = (uint32_t)f2bf(v[2*jp    ].z) | ((uint32_t)f2bf(v[2*jp    ].w) << 16);
        w.z = (uint32_t)f2bf(v[2*jp + 1].x) | ((uint32_t)f2bf(v[2*jp + 1].y) << 16);
        w.w = (uint32_t)f2bf(v[2*jp + 1].z) | ((uint32_t)f2bf(v[2*jp + 1].w) << 16);
        int slot = qtr * 4 + jp;
        *(uint4*)(alds + row * 256 + ((slot ^ (row & 7)) << 4)) = w;
    }
    __syncthreads();

    // A fragments + half-esq registers
    bf16x8 a[4][4];
    #pragma unroll
    for (int s = 0; s < 4; s++) {
        int ar = s * 16 + (lane & 15);
        #pragma unroll
        for (int ks = 0; ks < 4; ks++) {
            int slot = ks * 4 + (lane >> 4);
            a[s][ks] = *(const bf16x8*)(alds + ar * 256 + ((slot ^ (ar & 7)) << 4));
        }
    }
    float eh[4][4];
    #pragma unroll
    for (int s = 0; s < 4; s++)
        #pragma unroll
        for (int r = 0; r < 4; r++)
            eh[s][r] = esqh_lds[s * 16 + (lane >> 4) * 4 + r];

    int creg[8];
    #pragma unroll
    for (int c = 0; c < 8; c++) {
        if (c < 7) {
            #pragma unroll
            for (int ks = 0; ks < 4; ks++)
                bnext[ks] = *(const bf16x8*)(qb + (size_t)(c + 1) * 16 * DIM + ks * 32);
        }
        f32x4 acc[4];
        #pragma unroll
        for (int s = 0; s < 4; s++) acc[s] = (f32x4){0.f, 0.f, 0.f, 0.f};
        #pragma unroll
        for (int ks = 0; ks < 4; ks++) {
            #pragma unroll
            for (int s = 0; s < 4; s++)
                acc[s] = __builtin_amdgcn_mfma_f32_16x16x32_bf16(a[s][ks], bcur[ks], acc[s], 0, 0, 0);
        }
        int cl = 0;
        #pragma unroll
        for (int s = 0; s < 4; s++) {
            #pragma unroll
            for (int r = 0; r < 4; r++)
                cl += (acc[s][r] < tcv[c] - eh[s][r]) ? 1 : 0;   // esq + 2*dot + qsq < thr
        }
        cl += __shfl_xor(cl, 16);
        cl += __shfl_xor(cl, 32);
        creg[c] = cl;
        #pragma unroll
        for (int ks = 0; ks < 4; ks++) bcur[ks] = bnext[ks];
    }

    // one flush at kernel end, off every load's critical path
    if (lane < 16) {
        #pragma unroll
        for (int c = 0; c < 8; c++) {
            int col = colq + c * 16;
            if (USE_PART)
                part[(size_t)col * NBLK_PAD + blockIdx.x] = (unsigned short)creg[c];
            else
                atomicAdd(&cnt[col], creg[c]);
        }
    }
}

// Per (side,b)=key: sum this column's per-block partials (coalesced),
// gather/dedup filter matches, exact fp32 recompute, rank = sum + 1 - adj.
__global__ __launch_bounds__(64) void k_adjust(
    const float* __restrict__ ent,
    const float* __restrict__ qall, const float* __restrict__ qsq, const float* __restrict__ thr,
    const int* __restrict__ cnt, const unsigned short* __restrict__ part, int use_part,
    const int* __restrict__ mcnt, const int2* __restrict__ match,
    int* __restrict__ out)
{
    int key = blockIdx.x;
    int tid = threadIdx.x;
    __shared__ int ids[256];
    __shared__ int nm;
    if (tid == 0) nm = 0;
    __syncthreads();

    int acc = 0;
    if (use_part) {
        const unsigned short* p = part + (size_t)key * NBLK_PAD;
        for (int i = tid; i < NBLK; i += 64) acc += p[i];
    } else if (tid == 0) {
        acc = cnt[key];
    }

    int M = *mcnt; if (M > MCAP) M = MCAP;
    for (int i = tid; i < M; i += 64) {
        int2 e = match[i];
        if (e.x == key) { int p = atomicAdd(&nm, 1); if (p < 256) ids[p] = e.y; }
    }
    __syncthreads();
    int mm = nm < 256 ? nm : 256;
    const float* qv = qall + (size_t)key * DIM;
    float qq = qsq[key], th = thr[key];
    for (int i = tid; i < mm; i += 64) {
        int id = ids[i];
        bool dup = false;
        for (int j = 0; j < i; j++) if (ids[j] == id) { dup = true; break; }
        if (!dup) {
            const float* en = ent + (size_t)id * DIM;
            float es = 0.f, dot = 0.f;
            for (int d = 0; d < DIM; d++) { float x = en[d]; es += x * x; dot += x * qv[d]; }
            if (fmaxf(es + 2.f * dot + qq, 1e-12f) < th) acc--;
        }
    }
    #pragma unroll
    for (int off = 32; off; off >>= 1) acc += __shfl_xor(acc, off);
    if (tid == 0) out[key] = acc + 1;
}

extern "C" void kernel_launch(void* const* d_in, const int* in_sizes, int n_in,
                              void* d_out, int out_size, void* d_ws, size_t ws_size,
                              hipStream_t stream)
{
    const float* ent   = (const float*)d_in[0];
    const float* rel   = (const float*)d_in[1];
    const int*   heads = (const int*)d_in[2];
    const int*   rels  = (const int*)d_in[3];
    const int*   tails = (const int*)d_in[4];
    const int*   fh    = (const int*)d_in[5];
    const int*   fr    = (const int*)d_in[6];
    const int*   ft    = (const int*)d_in[7];
    int* out = (int*)d_out;

    char* ws = (char*)d_ws;
    float* qall = (float*)(ws + WS_QALL);
    float* qsq  = (float*)(ws + WS_QSQ);
    float* thr  = (float*)(ws + WS_THR);
    float* thc  = (float*)(ws + WS_THC);
    int*   cnt  = (int*)(ws + WS_CNT);
    int*   mcnt = (int*)(ws + WS_MCNT);
    int2*  match = (int2*)(ws + WS_MATCH);
    unsigned short* qbf  = (unsigned short*)(ws + WS_QBF);
    unsigned short* part = (unsigned short*)(ws + WS_PART);

    int use_part = (ws_size >= (size_t)WS_NEED) ? 1 : 0;

    k_prep<<<BSZ, 128, 0, stream>>>(ent, rel, heads, rels, tails,
                                    qall, qsq, thr, thc, cnt, mcnt, qbf);
    k_scanf<<<(FSZ + 255) / 256, 256, 0, stream>>>(heads, rels, tails, fh, fr, ft, mcnt, match);
    if (use_part)
        k_count<true><<<NBLK, 256, 0, stream>>>(ent, qbf, thc, cnt, part);
    else
        k_count<false><<<NBLK, 256, 0, stream>>>(ent, qbf, thc, cnt, part);
    k_adjust<<<2 * BSZ, 64, 0, stream>>>(ent, qall, qsq, thr, cnt, part, use_part,
                                         mcnt, match, out);
}

// Round 5
// 76.860 us; speedup vs baseline: 1.6003x; 1.6003x over previous
//
#include <hip/hip_runtime.h>
#include <cstdint>
#include <cstddef>

#define N_ENT 100000
#define DIM 128
#define BSZ 256
#define FSZ 20000
#define BM 64
#define NBLK 1563            // ceil(N_ENT / BM)
#define MCAP 8192

typedef __attribute__((ext_vector_type(8))) short bf16x8;
typedef __attribute__((ext_vector_type(4))) float f32x4;

// keep a value pinned in VGPRs (defeats LDS-reload rematerialization)
#define KEEP(x) asm volatile("" : "+v"(x))

// ---------------- ws layout ----------------
#define WS_QALL 0                               // [512][128] f32 exact queries
#define WS_QSQ  (512 * DIM * 4)                 // [512] f32
#define WS_THR  (WS_QSQ + 512 * 4)              // [512] f32
#define WS_THC  (WS_THR + 512 * 4)              // [512] f32  (thr - qsq) * 0.5
#define WS_CNT  (WS_THC + 512 * 4)              // [512] int  (atomic fallback)
#define WS_MCNT (WS_CNT + 512 * 4)              // [1] int + pad
#define WS_MATCH (WS_MCNT + 16)                 // [MCAP] int2
#define WS_QBF  (WS_MATCH + MCAP * 8)           // [512][128] bf16
#define WS_PART (WS_QBF + 512 * DIM * 2 + 64)   // [NBLK][512] u16, block-major (coalesced)
#define WS_NEED (WS_PART + (size_t)NBLK * 512 * 2)

__device__ inline unsigned short f2bf(float x) {
    union { float f; uint32_t u; } v; v.f = x;
    uint32_t u = v.u;
    u += 0x7fffu + ((u >> 16) & 1);   // RNE
    return (unsigned short)(u >> 16);
}

__global__ __launch_bounds__(128) void k_prep(
    const float* __restrict__ ent, const float* __restrict__ rel,
    const int* __restrict__ heads, const int* __restrict__ rels, const int* __restrict__ tails,
    float* __restrict__ qall, float* __restrict__ qsq, float* __restrict__ thr,
    float* __restrict__ thc, int* __restrict__ cnt, int* __restrict__ mcnt,
    unsigned short* __restrict__ qbf)
{
    int b = blockIdx.x;
    int d = threadIdx.x;
    if (b == 0 && d == 0) *mcnt = 0;
    int h = heads[b], r = rels[b], t = tails[b];
    float eh = ent[(size_t)h * DIM + d];
    float er = rel[(size_t)r * DIM + d];
    float et = ent[(size_t)t * DIM + d];
    float diff = eh + er - et;
    float q = er - et;
    float p = eh + er;
    qall[(size_t)b * DIM + d] = q;
    qall[(size_t)(BSZ + b) * DIM + d] = -p;
    qbf[(size_t)b * DIM + d] = f2bf(q);
    qbf[(size_t)(BSZ + b) * DIM + d] = f2bf(-p);
    float s0 = diff * diff, s1 = q * q, s2 = p * p;
    #pragma unroll
    for (int off = 32; off; off >>= 1) {
        s0 += __shfl_xor(s0, off);
        s1 += __shfl_xor(s1, off);
        s2 += __shfl_xor(s2, off);
    }
    __shared__ float part[2][3];
    int wave = threadIdx.x >> 6, lane = threadIdx.x & 63;
    if (lane == 0) { part[wave][0] = s0; part[wave][1] = s1; part[wave][2] = s2; }
    __syncthreads();
    if (threadIdx.x == 0) {
        float tsq = part[0][0] + part[1][0];
        float qq  = part[0][1] + part[1][1];
        float pp  = part[0][2] + part[1][2];
        float th = fmaxf(tsq, 1e-12f);
        thr[b] = th; thr[BSZ + b] = th;
        qsq[b] = qq; qsq[BSZ + b] = pp;
        thc[b] = (th - qq) * 0.5f;
        thc[BSZ + b] = (th - pp) * 0.5f;
        cnt[b] = 0;  cnt[BSZ + b] = 0;
    }
}

__global__ __launch_bounds__(256) void k_scanf(
    const int* __restrict__ heads, const int* __restrict__ rels, const int* __restrict__ tails,
    const int* __restrict__ fh, const int* __restrict__ fr, const int* __restrict__ ft,
    int* __restrict__ mcnt, int2* __restrict__ match)
{
    __shared__ int hh[BSZ], rr[BSZ], tt[BSZ];
    int tid = threadIdx.x;
    hh[tid] = heads[tid]; rr[tid] = rels[tid]; tt[tid] = tails[tid];
    __syncthreads();
    int f = blockIdx.x * 256 + tid;
    if (f >= FSZ) return;
    int vr = fr[f], vt = ft[f], vh = fh[f];
    for (int b = 0; b < BSZ; b++) {
        int rb = rr[b];
        if (vr == rb && vt == tt[b]) {
            int p = atomicAdd(mcnt, 1);
            if (p < MCAP) match[p] = make_int2(b, vh);
        }
        if (vr == rb && vh == hh[b]) {
            int p = atomicAdd(mcnt, 1);
            if (p < MCAP) match[p] = make_int2(BSZ + b, vt);
        }
    }
}

// MFMA count: 64-entity tile/block, 4 waves x 128 query cols each.
// A fragments pinned in VGPRs (KEEP), counts in registers, ZERO memory ops
// in the chunk loop except prefetched B loads. One contention-free flush at
// the end: coalesced u16 row part[block][0..511] (or atomic fallback).
template<bool USE_PART>
__global__ __launch_bounds__(256, 2) void k_count(
    const float* __restrict__ ent,
    const unsigned short* __restrict__ qbf,
    const float* __restrict__ thc,
    int* __restrict__ cnt, unsigned short* __restrict__ part)
{
    __shared__ __align__(16) char alds[BM * 256];   // 64 rows x 128 bf16, 16B-slot XOR swizzle
    __shared__ float esqh_lds[BM];                  // 0.5 * ||e_row||^2
    int tid = threadIdx.x;
    int lane = tid & 63, wave = tid >> 6;
    int base = blockIdx.x * BM;

    // B chunk-0 prefetch + per-col thresholds (hoisted)
    int colq = wave * 128 + (lane & 15);
    const unsigned short* qb = qbf + (size_t)colq * DIM + (lane >> 4) * 8;
    bf16x8 bcur[4], bnext[4];
    #pragma unroll
    for (int ks = 0; ks < 4; ks++)
        bcur[ks] = *(const bf16x8*)(qb + ks * 32);
    float tcv[8];
    #pragma unroll
    for (int c = 0; c < 8; c++) tcv[c] = thc[colq + c * 16];

    // stage A: 4 threads per row, 128B each, fully coalesced
    int row = tid >> 2, qtr = tid & 3;
    int n = base + row;
    bool valid = n < N_ENT;
    const float4* src = (const float4*)(ent + (size_t)n * DIM) + qtr * 8;
    float4 v[8];
    float ssq = 0.f;
    #pragma unroll
    for (int j = 0; j < 8; j++) {
        v[j] = valid ? src[j] : make_float4(0.f, 0.f, 0.f, 0.f);
        ssq += v[j].x * v[j].x + v[j].y * v[j].y + v[j].z * v[j].z + v[j].w * v[j].w;
    }
    ssq += __shfl_xor(ssq, 1);
    ssq += __shfl_xor(ssq, 2);
    if (qtr == 0) esqh_lds[row] = valid ? ssq * 0.5f : 1.5e38f;
    #pragma unroll
    for (int jp = 0; jp < 4; jp++) {
        uint4 w;
        w.x = (uint32_t)f2bf(v[2*jp    ].x) | ((uint32_t)f2bf(v[2*jp    ].y) << 16);
        w.y = (uint32_t)f2bf(v[2*jp    ].z) | ((uint32_t)f2bf(v[2*jp    ].w) << 16);
        w.z = (uint32_t)f2bf(v[2*jp + 1].x) | ((uint32_t)f2bf(v[2*jp + 1].y) << 16);
        w.w = (uint32_t)f2bf(v[2*jp + 1].z) | ((uint32_t)f2bf(v[2*jp + 1].w) << 16);
        int slot = qtr * 4 + jp;
        *(uint4*)(alds + row * 256 + ((slot ^ (row & 7)) << 4)) = w;
    }
    __syncthreads();

    // A fragments + half-esq -> registers, pinned so they are never re-read
    bf16x8 a[4][4];
    #pragma unroll
    for (int s = 0; s < 4; s++) {
        int ar = s * 16 + (lane & 15);
        #pragma unroll
        for (int ks = 0; ks < 4; ks++) {
            int slot = ks * 4 + (lane >> 4);
            a[s][ks] = *(const bf16x8*)(alds + ar * 256 + ((slot ^ (ar & 7)) << 4));
            KEEP(a[s][ks]);
        }
    }
    float eh[4][4];
    #pragma unroll
    for (int s = 0; s < 4; s++)
        #pragma unroll
        for (int r = 0; r < 4; r++) {
            eh[s][r] = esqh_lds[s * 16 + (lane >> 4) * 4 + r];
            KEEP(eh[s][r]);
        }

    int creg[8];
    #pragma unroll
    for (int c = 0; c < 8; c++) {
        if (c < 7) {
            #pragma unroll
            for (int ks = 0; ks < 4; ks++)
                bnext[ks] = *(const bf16x8*)(qb + (size_t)(c + 1) * 16 * DIM + ks * 32);
        }
        f32x4 acc[4];
        #pragma unroll
        for (int s = 0; s < 4; s++) acc[s] = (f32x4){0.f, 0.f, 0.f, 0.f};
        #pragma unroll
        for (int ks = 0; ks < 4; ks++) {
            #pragma unroll
            for (int s = 0; s < 4; s++)
                acc[s] = __builtin_amdgcn_mfma_f32_16x16x32_bf16(a[s][ks], bcur[ks], acc[s], 0, 0, 0);
        }
        int cl = 0;
        #pragma unroll
        for (int s = 0; s < 4; s++) {
            #pragma unroll
            for (int r = 0; r < 4; r++)
                cl += (acc[s][r] < tcv[c] - eh[s][r]) ? 1 : 0;   // esq + 2*dot + qsq < thr
        }
        cl += __shfl_xor(cl, 16);
        cl += __shfl_xor(cl, 32);
        creg[c] = cl;
        #pragma unroll
        for (int ks = 0; ks < 4; ks++) bcur[ks] = bnext[ks];
    }

    // single contention-free flush: block-major row => 1KB coalesced per block
    if (lane < 16) {
        #pragma unroll
        for (int c = 0; c < 8; c++) {
            int col = colq + c * 16;
            if (USE_PART)
                part[(size_t)blockIdx.x * 512 + col] = (unsigned short)creg[c];
            else
                atomicAdd(&cnt[col], creg[c]);
        }
    }
}

// Per (side,b)=key: sum this key's column over per-block partials,
// gather/dedup filter matches, exact fp32 recompute, rank = sum + 1 - adj.
__global__ __launch_bounds__(256) void k_adjust(
    const float* __restrict__ ent,
    const float* __restrict__ qall, const float* __restrict__ qsq, const float* __restrict__ thr,
    const int* __restrict__ cnt, const unsigned short* __restrict__ part, int use_part,
    const int* __restrict__ mcnt, const int2* __restrict__ match,
    int* __restrict__ out)
{
    int key = blockIdx.x;
    int tid = threadIdx.x;
    __shared__ int ids[256];
    __shared__ int nm;
    __shared__ int wsum[4];
    if (tid == 0) nm = 0;
    __syncthreads();

    int acc = 0;
    if (use_part) {
        for (int i = tid; i < NBLK; i += 256)
            acc += part[(size_t)i * 512 + key];
    } else if (tid == 0) {
        acc = cnt[key];
    }

    int M = *mcnt; if (M > MCAP) M = MCAP;
    for (int i = tid; i < M; i += 256) {
        int2 e = match[i];
        if (e.x == key) { int p = atomicAdd(&nm, 1); if (p < 256) ids[p] = e.y; }
    }
    __syncthreads();
    int mm = nm < 256 ? nm : 256;
    const float* qv = qall + (size_t)key * DIM;
    float qq = qsq[key], th = thr[key];
    for (int i = tid; i < mm; i += 256) {
        int id = ids[i];
        bool dup = false;
        for (int j = 0; j < i; j++) if (ids[j] == id) { dup = true; break; }
        if (!dup) {
            const float* en = ent + (size_t)id * DIM;
            float es = 0.f, dot = 0.f;
            for (int d = 0; d < DIM; d++) { float x = en[d]; es += x * x; dot += x * qv[d]; }
            if (fmaxf(es + 2.f * dot + qq, 1e-12f) < th) acc--;
        }
    }
    #pragma unroll
    for (int off = 32; off; off >>= 1) acc += __shfl_xor(acc, off);
    int lane = tid & 63, wv = tid >> 6;
    if (lane == 0) wsum[wv] = acc;
    __syncthreads();
    if (tid == 0) out[key] = wsum[0] + wsum[1] + wsum[2] + wsum[3] + 1;
}

extern "C" void kernel_launch(void* const* d_in, const int* in_sizes, int n_in,
                              void* d_out, int out_size, void* d_ws, size_t ws_size,
                              hipStream_t stream)
{
    const float* ent   = (const float*)d_in[0];
    const float* rel   = (const float*)d_in[1];
    const int*   heads = (const int*)d_in[2];
    const int*   rels  = (const int*)d_in[3];
    const int*   tails = (const int*)d_in[4];
    const int*   fh    = (const int*)d_in[5];
    const int*   fr    = (const int*)d_in[6];
    const int*   ft    = (const int*)d_in[7];
    int* out = (int*)d_out;

    char* ws = (char*)d_ws;
    float* qall = (float*)(ws + WS_QALL);
    float* qsq  = (float*)(ws + WS_QSQ);
    float* thr  = (float*)(ws + WS_THR);
    float* thc  = (float*)(ws + WS_THC);
    int*   cnt  = (int*)(ws + WS_CNT);
    int*   mcnt = (int*)(ws + WS_MCNT);
    int2*  match = (int2*)(ws + WS_MATCH);
    unsigned short* qbf  = (unsigned short*)(ws + WS_QBF);
    unsigned short* part = (unsigned short*)(ws + WS_PART);

    int use_part = (ws_size >= (size_t)WS_NEED) ? 1 : 0;

    k_prep<<<BSZ, 128, 0, stream>>>(ent, rel, heads, rels, tails,
                                    qall, qsq, thr, thc, cnt, mcnt, qbf);
    k_scanf<<<(FSZ + 255) / 256, 256, 0, stream>>>(heads, rels, tails, fh, fr, ft, mcnt, match);
    if (use_part)
        k_count<true><<<NBLK, 256, 0, stream>>>(ent, qbf, thc, cnt, part);
    else
        k_count<false><<<NBLK, 256, 0, stream>>>(ent, qbf, thc, cnt, part);
    k_adjust<<<2 * BSZ, 256, 0, stream>>>(ent, qall, qsq, thr, cnt, part, use_part,
                                          mcnt, match, out);
}